// Round 7
// baseline (263.368 us; speedup 1.0000x reference)
//
#include <hip/hip_runtime.h>
#include <math.h>

#define Bb 64
#define Nn 512
#define Dd 300

typedef __attribute__((ext_vector_type(8))) short bfrag;   // 8 bf16 = 4 VGPRs
typedef __attribute__((ext_vector_type(4))) float f4;      // MFMA accumulator
typedef __attribute__((ext_vector_type(4))) unsigned u4;
typedef __attribute__((ext_vector_type(2))) unsigned u2;

union BF { unsigned u[4]; bfrag v; u4 q; };

__device__ inline unsigned bfr(float x){            // f32 -> bf16 bits, RNE
    union{float f;unsigned u;}v; v.f=x;
    return (v.u + 0x7FFFu + ((v.u>>16)&1u))>>16;
}
__device__ inline unsigned pk_rne(float a, float b){ return bfr(a) | (bfr(b)<<16); }
__device__ inline unsigned pk_tr(float a, float b){  // truncation pack (cheap)
    union{float f;unsigned u;} ua, ub; ua.f=a; ub.f=b;
    return (ua.u>>16) | (ub.u & 0xFFFF0000u);
}
// W-frag bytes live in d_out slot bytes [608, 608+512) of slots f>>9
__device__ inline char* wadr(char* dout, unsigned f){
    return dout + (size_t)(f>>9)*1200u + 608u + (f&511u);
}
__device__ inline void async16(const char* g, char* l){
    __builtin_amdgcn_global_load_lds(
        (const __attribute__((address_space(1))) void*)g,
        (__attribute__((address_space(3))) void*)l, 16, 0, 0);
}

// Merged (b,mt) tile: 38400 B = [K zone 19200 | V zone 19200]
//  K: kc9 sub-tile [0,768): m*24 + (e-288)*2
//     kc<9:  768 + kc*2048 + ((e>>3)&3)*512 + m*16 + (e&7)*2
//  V: d<288:  19200 + (d>>4)*1024 + (m>>3)*256 + (d&15)*16 + (m&7)*2
//     d>=288: 19200 + 18432 + (m>>3)*192 + (d-288)*16 + (m&7)*2
#define TSZ 38400
#define VOFF 19200

// Workspace layout for the kv-split path:
//  [0, 39321600)                : merged tiles (always)
//  [39321600, 119013376)        : O partials f32 [b][row][kvs2][304]
//  [119013376, 119275520)       : l partials f32 [b][row][kvs2]
#define PART_O_OFF 39321600u
#define PART_L_OFF 119013376u
#define WS_NEED    119275520ull

// ---------- Kernel A: W -> bf16 frag-tiles in d_out high bytes -------------
// f = sel*194560 + kc*19456 + g*4864 + n*16  (+ (k&7)*2 inside)
__global__ __launch_bounds__(256)
void wprep(const float* __restrict__ wq, const float* __restrict__ wk,
           char* __restrict__ dout)
{
    const int sel = blockIdx.x / 10, kc = blockIdx.x % 10;
    const float* W = sel ? wk : wq;
    const int n = blockIdx.y*152 + threadIdx.x;
    if (threadIdx.x < 152 && n < 304) {
        unsigned uu[16];
        #pragma unroll
        for (int j = 0; j < 16; ++j) uu[j] = 0;
        if (n < Dd) {
            const float* wr = W + (size_t)n*Dd + kc*32;
            int nv4 = (kc < 9) ? 8 : 3;        // kc=9: k 288..299 only
            #pragma unroll
            for (int i = 0; i < 8; ++i) {
                if (i < nv4) {
                    float4 v = *(const float4*)(wr + i*4);
                    uu[2*i  ] = pk_rne(v.x, v.y);
                    uu[2*i+1] = pk_rne(v.z, v.w);
                }
            }
        }
        unsigned fb = (unsigned)(sel*194560 + kc*19456 + n*16);
        #pragma unroll
        for (int g = 0; g < 4; ++g) {
            u4 q; q.x = uu[4*g+0]; q.y = uu[4*g+1]; q.z = uu[4*g+2]; q.w = uu[4*g+3];
            *(u4*)wadr(dout, fb + g*4864) = q;
        }
    }
}

// ---------- Kernel B: fused projection GEMM (blocks 0..511) +  -------------
//            concepts->V-zone cast (blocks 512..1023, 2 tiles each)
__global__ __launch_bounds__(512)
void projcast(const float* __restrict__ concepts, const float* __restrict__ ocr,
              const float* __restrict__ bq, const float* __restrict__ bk,
              char* __restrict__ dout, char* __restrict__ tiles)
{
    __shared__ char Wl[2][19456];
    const int bx = blockIdx.x;
    const int t  = threadIdx.x;

    if (bx >= 512) {
        // ---- V-cast role: two (b,mt) tiles per block ----
        const int half = t >> 8, tt = t & 255;
        const int tileIdx = (bx - 512)*2 + half;
        const int mt = tileIdx & 15, b = tileIdx >> 4;
        char* vz = tiles + ((size_t)(b*16 + mt))*TSZ + VOFF;
        for (int task = tt; task < 300; task += 256) {
            int m8 = task / 75, d4 = task - m8*75;     // m8:0..3, d4:0..74
            const float* src = concepts + ((size_t)(b*Nn + mt*32 + m8*8))*Dd + d4*4;
            float4 r[8];
            #pragma unroll
            for (int i = 0; i < 8; ++i) r[i] = *(const float4*)(src + (size_t)i*Dd);
            #pragma unroll
            for (int dd = 0; dd < 4; ++dd) {
                int d = d4*4 + dd;
                float x[8];
                #pragma unroll
                for (int i = 0; i < 8; ++i)
                    x[i] = (dd==0) ? r[i].x : (dd==1) ? r[i].y : (dd==2) ? r[i].z : r[i].w;
                u4 q; q.x = pk_rne(x[0],x[1]); q.y = pk_rne(x[2],x[3]);
                      q.z = pk_rne(x[4],x[5]); q.w = pk_rne(x[6],x[7]);
                char* dst = (d < 288)
                    ? vz + (d>>4)*1024 + m8*256 + (d&15)*16
                    : vz + 18432 + m8*192 + (d-288)*16;
                *(u4*)dst = q;
            }
        }
        return;
    }

    // ---- projection role: 128 rows, 8 waves ----
    const int w = t >> 6, lane = t & 63, ln = lane & 15, quad = lane >> 4;
    const int sel = bx >> 8;
    const float* X    = sel ? ocr : concepts;
    const float* bias = sel ? bk  : bq;
    const int r0w = (bx & 255)*128 + w*16;
    const float* xr = X + (size_t)(r0w + ln)*Dd;

    const unsigned selbase = (unsigned)sel*194560u;
    #define STAGE_W8(buf, kc) \
        for (int c = w; c < 19; c += 8) \
            async16((const char*)wadr(dout, selbase + (unsigned)(kc)*19456u + c*1024u + lane*16u), \
                    &Wl[buf][c*1024 + lane*16]);

    f4 acc[19];
    #pragma unroll
    for (int i = 0; i < 19; ++i) acc[i] = (f4){0.f,0.f,0.f,0.f};

    STAGE_W8(0, 0);
    __syncthreads();

    for (int kc = 0; kc < 10; ++kc) {
        const int cur = kc & 1;
        if (kc < 9) { STAGE_W8(1 - cur, kc + 1); }
        BF a;
        if (kc < 9) {
            float4 v0 = *(const float4*)(xr + kc*32 + quad*8);
            float4 v1 = *(const float4*)(xr + kc*32 + quad*8 + 4);
            a.u[0]=pk_tr(v0.x,v0.y); a.u[1]=pk_tr(v0.z,v0.w);
            a.u[2]=pk_tr(v1.x,v1.y); a.u[3]=pk_tr(v1.z,v1.w);
        } else {
            a.u[0]=0; a.u[1]=0; a.u[2]=0; a.u[3]=0;
            if (quad == 0) {
                float4 v0 = *(const float4*)(xr + 288);
                float4 v1 = *(const float4*)(xr + 292);
                a.u[0]=pk_tr(v0.x,v0.y); a.u[1]=pk_tr(v0.z,v0.w);
                a.u[2]=pk_tr(v1.x,v1.y); a.u[3]=pk_tr(v1.z,v1.w);
            } else if (quad == 1) {
                float4 v0 = *(const float4*)(xr + 296);
                a.u[0]=pk_tr(v0.x,v0.y); a.u[1]=pk_tr(v0.z,v0.w);
            }
        }
        #pragma unroll
        for (int nt = 0; nt < 19; ++nt) {
            BF bfv; bfv.q = *(const u4*)&Wl[cur][quad*4864 + nt*256 + ln*16];
            acc[nt] = __builtin_amdgcn_mfma_f32_16x16x32_bf16(a.v, bfv.v, acc[nt], 0,0,0);
        }
        __syncthreads();
    }

    const float QSCALE = 0.057735026918962584f;   // 1/sqrt(300)
    #pragma unroll
    for (int nt = 0; nt < 19; ++nt) {
        int e = nt*16 + ln;
        if (sel == 0) {
            #pragma unroll
            for (int reg = 0; reg < 4; ++reg) {
                int r = r0w + quad*4 + reg;
                short val = (e < Dd) ? (short)bfr((acc[nt][reg] + bias[e])*QSCALE) : (short)0;
                *(short*)(dout + (size_t)r*1200 + e*2) = val;   // e 300..303 zeroed
            }
        } else if (e < Dd) {
            float bv = bias[e];
            #pragma unroll
            for (int reg = 0; reg < 4; ++reg) {
                int r = r0w + quad*4 + reg;
                int b = r >> 9, m = r & 511, mt = m >> 5, ml = m & 31;
                char* tile = tiles + ((size_t)(b*16 + mt))*TSZ;
                short val = (short)bfr(acc[nt][reg] + bv);
                if (e < 288)
                    *(short*)(tile + 768 + (e>>5)*2048 + ((e>>3)&3)*512 + ml*16 + (e&7)*2) = val;
                else
                    *(short*)(tile + ml*24 + (e-288)*2) = val;
            }
        }
    }
}

// stage one full 38400-B merged tile: 37 x 1KB chunks + 512-B tail (lane<32)
#define STAGE_TILE(SRC, DST) do { \
        const char* s_ = (SRC); char* d_ = (DST); \
        for (int c = w; c < 38; c += 8) \
            if (c < 37 || lane < 32) \
                async16(s_ + c*1024 + lane*16, d_ + c*1024 + lane*16); \
    } while (0)

// ---------- Kernel D (fallback): round-4/5 attn8, proven 64 us -------------
__global__ __launch_bounds__(512, 2)
void attn8(char* __restrict__ dout, const char* __restrict__ tiles,
           const float* __restrict__ ocr, const int* __restrict__ mask,
           const float* __restrict__ lnw, const float* __restrict__ lnb)
{
    __shared__ __align__(16) char Tb[2][TSZ];
    const int t = threadIdx.x;
    const int w = t >> 6, lane = t & 63, ln = lane & 15, quad = lane >> 4;
    const int b = blockIdx.x, n0 = blockIdx.y*128;
    const int nlane = n0 + w*16 + ln;

    const char* qb = dout + (size_t)(b*Nn + nlane)*1200;
    bfrag qf[10];
    #pragma unroll
    for (int kc = 0; kc < 9; ++kc)
        qf[kc] = *(const bfrag*)(qb + kc*64 + quad*16);
    {
        BF z; z.u[0]=z.u[1]=z.u[2]=z.u[3]=0;
        if (quad < 2) z.q = *(const u4*)(qb + 576 + quad*16);
        qf[9] = z.v;
    }

    f4 oacc[19];
    #pragma unroll
    for (int i = 0; i < 19; ++i) oacc[i] = (f4){0.f,0.f,0.f,0.f};
    float lrun = 0.f;
    const char* tb = tiles + (size_t)b*16*TSZ;

    STAGE_TILE(tb, Tb[0]);
    __syncthreads();

    for (int mt = 0; mt < 16; ++mt) {
        const char* Kz = Tb[mt & 1];
        const char* Vz = Kz + VOFF;
        if (mt < 15) STAGE_TILE(tb + (size_t)(mt+1)*TSZ, Tb[1 - (mt & 1)]);

        f4 slo = (f4){0.f,0.f,0.f,0.f}, shi = (f4){0.f,0.f,0.f,0.f};
        __builtin_amdgcn_s_setprio(1);
        #pragma unroll
        for (int kc = 0; kc < 9; ++kc) {
            bfrag alo = *(const bfrag*)(Kz + 768 + kc*2048 + quad*512 + ln*16);
            bfrag ahi = *(const bfrag*)(Kz + 768 + kc*2048 + quad*512 + 256 + ln*16);
            slo = __builtin_amdgcn_mfma_f32_16x16x32_bf16(alo, qf[kc], slo, 0,0,0);
            shi = __builtin_amdgcn_mfma_f32_16x16x32_bf16(ahi, qf[kc], shi, 0,0,0);
        }
        {
            BF alo, ahi;
            alo.u[0]=alo.u[1]=alo.u[2]=alo.u[3]=0;
            ahi.u[0]=ahi.u[1]=ahi.u[2]=ahi.u[3]=0;
            if (quad < 2) {
                u2 x0 = *(const u2*)(Kz + ln*24 + quad*16);
                u2 x1 = *(const u2*)(Kz + ln*24 + quad*16 + 8);
                alo.u[0]=x0.x; alo.u[1]=x0.y; alo.u[2]=x1.x; alo.u[3]=x1.y;
                u2 y0 = *(const u2*)(Kz + (16+ln)*24 + quad*16);
                u2 y1 = *(const u2*)(Kz + (16+ln)*24 + quad*16 + 8);
                ahi.u[0]=y0.x; ahi.u[1]=y0.y; ahi.u[2]=y1.x; ahi.u[3]=y1.y;
            }
            slo = __builtin_amdgcn_mfma_f32_16x16x32_bf16(alo.v, qf[9], slo, 0,0,0);
            shi = __builtin_amdgcn_mfma_f32_16x16x32_bf16(ahi.v, qf[9], shi, 0,0,0);
        }
        __builtin_amdgcn_s_setprio(0);

        float elo[4], ehi[4], ls = 0.f;
        #pragma unroll
        for (int reg = 0; reg < 4; ++reg) {
            elo[reg] = __expf(slo[reg]);
            ehi[reg] = __expf(shi[reg]);
            ls += elo[reg] + ehi[reg];
        }
        ls += __shfl_xor(ls, 16);
        ls += __shfl_xor(ls, 32);
        lrun += ls;

        unsigned lo01 = pk_rne(elo[0], elo[1]), lo23 = pk_rne(elo[2], elo[3]);
        unsigned hi01 = pk_rne(ehi[0], ehi[1]), hi23 = pk_rne(ehi[2], ehi[3]);
        int sA = 2*(quad & 1)*16 + ln, sB = sA + 16;
        unsigned l0 = (unsigned)__shfl((int)lo01, sA);
        unsigned l1 = (unsigned)__shfl((int)lo23, sA);
        unsigned l2 = (unsigned)__shfl((int)lo01, sB);
        unsigned l3 = (unsigned)__shfl((int)lo23, sB);
        unsigned h0 = (unsigned)__shfl((int)hi01, sA);
        unsigned h1 = (unsigned)__shfl((int)hi23, sA);
        unsigned h2 = (unsigned)__shfl((int)hi01, sB);
        unsigned h3 = (unsigned)__shfl((int)hi23, sB);
        BF p;
        bool useHi = quad >= 2;
        p.u[0] = useHi ? h0 : l0; p.u[1] = useHi ? h1 : l1;
        p.u[2] = useHi ? h2 : l2; p.u[3] = useHi ? h3 : l3;

        __builtin_amdgcn_s_setprio(1);
        #pragma unroll
        for (int nt = 0; nt < 18; ++nt) {
            bfrag vf = *(const bfrag*)(Vz + nt*1024 + lane*16);
            oacc[nt] = __builtin_amdgcn_mfma_f32_16x16x32_bf16(p.v, vf, oacc[nt], 0,0,0);
        }
        {
            BF vf; vf.u[0]=vf.u[1]=vf.u[2]=vf.u[3]=0;
            if (ln < 12) vf.q = *(const u4*)(Vz + 18432 + quad*192 + ln*16);
            oacc[18] = __builtin_amdgcn_mfma_f32_16x16x32_bf16(p.v, vf.v, oacc[18], 0,0,0);
        }
        __builtin_amdgcn_s_setprio(0);

        __syncthreads();
    }

    float invl[4];
    #pragma unroll
    for (int reg = 0; reg < 4; ++reg) invl[reg] = 1.0f / __shfl(lrun, quad*4 + reg);
    #pragma unroll
    for (int reg = 0; reg < 4; ++reg) {
        int r = b*Nn + n0 + w*16 + quad*4 + reg;
        int mr = mask[r];
        float xs[19], s = 0.f, ss = 0.f;
        #pragma unroll
        for (int nt = 0; nt < 19; ++nt) {
            int d = nt*16 + ln;
            float x = 0.f;
            if (d < Dd) x = oacc[nt][reg]*invl[reg] + ocr[(size_t)r*Dd + d];
            xs[nt] = x; s += x; ss += x*x;
        }
        #pragma unroll
        for (int off = 1; off < 16; off <<= 1) {
            s += __shfl_xor(s, off); ss += __shfl_xor(ss, off);
        }
        float mu   = s * (1.0f/Dd);
        float var  = ss * (1.0f/Dd) - mu*mu;
        float rstd = rsqrtf(var + 1e-5f);
        #pragma unroll
        for (int nt = 0; nt < 19; ++nt) {
            int d = nt*16 + ln;
            if (d < Dd) {
                float y = mr ? (xs[nt]-mu)*rstd*lnw[d] + lnb[d] : lnw[d] + lnb[d];
                *(float*)(dout + (size_t)r*1200 + d*4) = y;
            }
        }
    }
}

// ---------- Kernel E: kv-split attention pass (occupancy experiment) -------
// Same per-block structure as attn8 but each block handles 8 of the 16 KV
// tiles -> grid (64,4,2) = 512 blocks -> 2 blocks/CU = 16 waves/CU (2x the
// occupancy of every prior variant). Unnormalized softmax makes the split
// associative: partials (O_i, l_i) just sum. Partials -> workspace f32.
__global__ __launch_bounds__(512, 4)
void attnA(char* __restrict__ dout, char* __restrict__ ws)
{
    const char* tiles = ws;
    float* Pt = (float*)(ws + PART_O_OFF);
    float* Lt = (float*)(ws + PART_L_OFF);
    __shared__ __align__(16) char Tb[2][TSZ];
    const int t = threadIdx.x;
    const int w = t >> 6, lane = t & 63, ln = lane & 15, quad = lane >> 4;
    const int b = blockIdx.x, n0 = blockIdx.y*128, kvs = blockIdx.z;
    const int nlane = n0 + w*16 + ln;

    const char* qb = dout + (size_t)(b*Nn + nlane)*1200;
    bfrag qf[10];
    #pragma unroll
    for (int kc = 0; kc < 9; ++kc)
        qf[kc] = *(const bfrag*)(qb + kc*64 + quad*16);
    {
        BF z; z.u[0]=z.u[1]=z.u[2]=z.u[3]=0;
        if (quad < 2) z.q = *(const u4*)(qb + 576 + quad*16);
        qf[9] = z.v;
    }

    f4 oacc[19];
    #pragma unroll
    for (int i = 0; i < 19; ++i) oacc[i] = (f4){0.f,0.f,0.f,0.f};
    float lrun = 0.f;
    const char* tb = tiles + (size_t)(b*16 + kvs*8)*TSZ;   // this block's 8 tiles

    STAGE_TILE(tb, Tb[0]);
    __syncthreads();

    for (int j = 0; j < 8; ++j) {
        const char* Kz = Tb[j & 1];
        const char* Vz = Kz + VOFF;
        if (j < 7) STAGE_TILE(tb + (size_t)(j+1)*TSZ, Tb[1 - (j & 1)]);

        f4 slo = (f4){0.f,0.f,0.f,0.f}, shi = (f4){0.f,0.f,0.f,0.f};
        __builtin_amdgcn_s_setprio(1);
        #pragma unroll
        for (int kc = 0; kc < 9; ++kc) {
            bfrag alo = *(const bfrag*)(Kz + 768 + kc*2048 + quad*512 + ln*16);
            bfrag ahi = *(const bfrag*)(Kz + 768 + kc*2048 + quad*512 + 256 + ln*16);
            slo = __builtin_amdgcn_mfma_f32_16x16x32_bf16(alo, qf[kc], slo, 0,0,0);
            shi = __builtin_amdgcn_mfma_f32_16x16x32_bf16(ahi, qf[kc], shi, 0,0,0);
        }
        {
            BF alo, ahi;
            alo.u[0]=alo.u[1]=alo.u[2]=alo.u[3]=0;
            ahi.u[0]=ahi.u[1]=ahi.u[2]=ahi.u[3]=0;
            if (quad < 2) {
                u2 x0 = *(const u2*)(Kz + ln*24 + quad*16);
                u2 x1 = *(const u2*)(Kz + ln*24 + quad*16 + 8);
                alo.u[0]=x0.x; alo.u[1]=x0.y; alo.u[2]=x1.x; alo.u[3]=x1.y;
                u2 y0 = *(const u2*)(Kz + (16+ln)*24 + quad*16);
                u2 y1 = *(const u2*)(Kz + (16+ln)*24 + quad*16 + 8);
                ahi.u[0]=y0.x; ahi.u[1]=y0.y; ahi.u[2]=y1.x; ahi.u[3]=y1.y;
            }
            slo = __builtin_amdgcn_mfma_f32_16x16x32_bf16(alo.v, qf[9], slo, 0,0,0);
            shi = __builtin_amdgcn_mfma_f32_16x16x32_bf16(ahi.v, qf[9], shi, 0,0,0);
        }
        __builtin_amdgcn_s_setprio(0);

        float elo[4], ehi[4], ls = 0.f;
        #pragma unroll
        for (int reg = 0; reg < 4; ++reg) {
            elo[reg] = __expf(slo[reg]);
            ehi[reg] = __expf(shi[reg]);
            ls += elo[reg] + ehi[reg];
        }
        ls += __shfl_xor(ls, 16);
        ls += __shfl_xor(ls, 32);
        lrun += ls;

        unsigned lo01 = pk_rne(elo[0], elo[1]), lo23 = pk_rne(elo[2], elo[3]);
        unsigned hi01 = pk_rne(ehi[0], ehi[1]), hi23 = pk_rne(ehi[2], ehi[3]);
        int sA = 2*(quad & 1)*16 + ln, sB = sA + 16;
        unsigned l0 = (unsigned)__shfl((int)lo01, sA);
        unsigned l1 = (unsigned)__shfl((int)lo23, sA);
        unsigned l2 = (unsigned)__shfl((int)lo01, sB);
        unsigned l3 = (unsigned)__shfl((int)lo23, sB);
        unsigned h0 = (unsigned)__shfl((int)hi01, sA);
        unsigned h1 = (unsigned)__shfl((int)hi23, sA);
        unsigned h2 = (unsigned)__shfl((int)hi01, sB);
        unsigned h3 = (unsigned)__shfl((int)hi23, sB);
        BF p;
        bool useHi = quad >= 2;
        p.u[0] = useHi ? h0 : l0; p.u[1] = useHi ? h1 : l1;
        p.u[2] = useHi ? h2 : l2; p.u[3] = useHi ? h3 : l3;

        __builtin_amdgcn_s_setprio(1);
        #pragma unroll
        for (int nt = 0; nt < 18; ++nt) {
            bfrag vf = *(const bfrag*)(Vz + nt*1024 + lane*16);
            oacc[nt] = __builtin_amdgcn_mfma_f32_16x16x32_bf16(p.v, vf, oacc[nt], 0,0,0);
        }
        {
            BF vf; vf.u[0]=vf.u[1]=vf.u[2]=vf.u[3]=0;
            if (ln < 12) vf.q = *(const u4*)(Vz + 18432 + quad*192 + ln*16);
            oacc[18] = __builtin_amdgcn_mfma_f32_16x16x32_bf16(p.v, vf.v, oacc[18], 0,0,0);
        }
        __builtin_amdgcn_s_setprio(0);

        __syncthreads();
    }

    // write partials: rows quad*4+reg (this wave covers rows w*16..w*16+15)
    const int rbase = b*Nn + n0 + w*16;
    if (lane < 16)
        Lt[(size_t)(rbase + lane)*2 + kvs] = lrun;   // lane i holds row i's l
    #pragma unroll
    for (int reg = 0; reg < 4; ++reg) {
        size_t rowoff = ((size_t)(rbase + quad*4 + reg)*2 + kvs)*304;
        #pragma unroll
        for (int nt = 0; nt < 19; ++nt)
            Pt[rowoff + nt*16 + ln] = oacc[nt][reg];
    }
}

// ---------- Kernel F: partial reduce + LN epilogue -------------------------
// One wave per row at a time; lane covers cols c = lane + 64k. Masked rows
// skip partial reads entirely (output = lnw+lnb, verified rounds 1-5).
__global__ __launch_bounds__(256)
void attnB(const char* __restrict__ ws, char* __restrict__ dout,
           const float* __restrict__ ocr, const int* __restrict__ mask,
           const float* __restrict__ lnw, const float* __restrict__ lnb)
{
    const float* Pt = (const float*)(ws + PART_O_OFF);
    const float* Lt = (const float*)(ws + PART_L_OFF);
    const int wv = threadIdx.x >> 6, lane = threadIdx.x & 63;
    for (int i = 0; i < 16; ++i) {
        int r = blockIdx.x*64 + wv*16 + i;
        int mr = mask[r];
        if (!mr) {
            for (int c = lane; c < Dd; c += 64)
                *(float*)(dout + (size_t)r*1200 + c*4) = lnw[c] + lnb[c];
            continue;
        }
        float invl = 1.0f / (Lt[(size_t)r*2] + Lt[(size_t)r*2 + 1]);
        const float* p0 = Pt + (size_t)r*2*304;
        const float* p1 = p0 + 304;
        float x[5]; float s = 0.f, ss = 0.f;
        #pragma unroll
        for (int k = 0; k < 5; ++k) {
            int c = lane + k*64;
            float v = 0.f;
            if (c < Dd)
                v = (p0[c] + p1[c])*invl + ocr[(size_t)r*Dd + c];
            x[k] = v; s += v; ss += v*v;
        }
        #pragma unroll
        for (int off = 1; off < 64; off <<= 1) {
            s += __shfl_xor(s, off); ss += __shfl_xor(ss, off);
        }
        float mu   = s * (1.0f/Dd);
        float var  = ss * (1.0f/Dd) - mu*mu;
        float rstd = rsqrtf(var + 1e-5f);
        #pragma unroll
        for (int k = 0; k < 5; ++k) {
            int c = lane + k*64;
            if (c < Dd)
                *(float*)(dout + (size_t)r*1200 + c*4) = (x[k]-mu)*rstd*lnw[c] + lnb[c];
        }
    }
}

extern "C" void kernel_launch(void* const* d_in, const int* in_sizes, int n_in,
                              void* d_out, int out_size, void* d_ws, size_t ws_size,
                              hipStream_t stream)
{
    const float* concepts = (const float*)d_in[0];
    const float* ocr      = (const float*)d_in[1];
    const int*   mask     = (const int*)d_in[2];
    const float* wq  = (const float*)d_in[3];
    const float* bq  = (const float*)d_in[4];
    const float* wk  = (const float*)d_in[5];
    const float* bk  = (const float*)d_in[6];
    const float* lnw = (const float*)d_in[7];
    const float* lnb = (const float*)d_in[8];

    char* dout  = (char*)d_out;
    char* tiles = (char*)d_ws;   // merged tiles at offset 0 (both paths)

    wprep   <<<dim3(20, 2), 256, 0, stream>>>(wq, wk, dout);
    projcast<<<dim3(1024),  512, 0, stream>>>(concepts, ocr, bq, bk, dout, tiles);

    if (ws_size >= WS_NEED) {
        // kv-split path: 512 blocks -> 2/CU -> 16 waves/CU
        attnA<<<dim3(64, 4, 2), 512, 0, stream>>>(dout, (char*)d_ws);
        attnB<<<dim3(512),      256, 0, stream>>>((const char*)d_ws, dout,
                                                  ocr, mask, lnw, lnb);
    } else {
        // fallback: proven round-4/5 configuration
        attn8<<<dim3(64, 4), 512, 0, stream>>>(dout, tiles, ocr, mask, lnw, lnb);
    }
}

// Round 9
// 230.813 us; speedup vs baseline: 1.1410x; 1.1410x over previous
//
#include <hip/hip_runtime.h>
#include <math.h>

#define Bb 64
#define Nn 512
#define Dd 300

typedef __attribute__((ext_vector_type(8))) short bfrag;   // 8 bf16 = 4 VGPRs
typedef __attribute__((ext_vector_type(4))) float f4;      // MFMA accumulator
typedef __attribute__((ext_vector_type(4))) unsigned u4;
typedef __attribute__((ext_vector_type(2))) unsigned u2;

union BF { unsigned u[4]; bfrag v; u4 q; };

__device__ inline unsigned bfr(float x){            // f32 -> bf16 bits, RNE
    union{float f;unsigned u;}v; v.f=x;
    return (v.u + 0x7FFFu + ((v.u>>16)&1u))>>16;
}
__device__ inline unsigned pk_rne(float a, float b){ return bfr(a) | (bfr(b)<<16); }
__device__ inline unsigned pk_tr(float a, float b){  // truncation pack (cheap)
    union{float f;unsigned u;} ua, ub; ua.f=a; ub.f=b;
    return (ua.u>>16) | (ub.u & 0xFFFF0000u);
}
// W-frag bytes live in d_out slot bytes [608, 608+512) of slots f>>9
__device__ inline char* wadr(char* dout, unsigned f){
    return dout + (size_t)(f>>9)*1200u + 608u + (f&511u);
}
__device__ inline void async16(const char* g, char* l){
    __builtin_amdgcn_global_load_lds(
        (const __attribute__((address_space(1))) void*)g,
        (__attribute__((address_space(3))) void*)l, 16, 0, 0);
}

// Merged (b,mt) tile: 38400 B = [K zone 19200 | V zone 19200]
//  K: kc9 sub-tile [0,768): m*24 + (e-288)*2
//     kc<9:  768 + kc*2048 + ((e>>3)&3)*512 + m*16 + (e&7)*2
//  V: d<288:  19200 + (d>>4)*1024 + (m>>3)*256 + (d&15)*16 + (m&7)*2
//     d>=288: 19200 + 18432 + (m>>3)*192 + (d-288)*16 + (m&7)*2
#define TSZ 38400
#define VOFF 19200

// Workspace: tiles [0, 39321600) ; row-compaction tables after
// (ws >= 119 MB proven in round 7, we use only ~39.5 MB)
#define RIDX_OFF 39321600u                   // int32 idx[64][512]
#define RCNT_OFF (RIDX_OFF + 64u*512u*4u)    // int32 cnt[64]

// ---------- Kernel A: W -> frag-tiles (bx<20)  +  row compaction (bx>=20) --
__global__ __launch_bounds__(512)
void wridx(const float* __restrict__ wq, const float* __restrict__ wk,
           const int* __restrict__ mask, char* __restrict__ dout,
           char* __restrict__ ws)
{
    const int bx = blockIdx.x, t = threadIdx.x;
    if (bx < 20) {
        // W prep: f = sel*194560 + kc*19456 + g*4864 + n*16
        const int sel = bx / 10, kc = bx % 10;
        const float* W = sel ? wk : wq;
        const int n = t;
        if (n < 304) {
            unsigned uu[16];
            #pragma unroll
            for (int j = 0; j < 16; ++j) uu[j] = 0;
            if (n < Dd) {
                const float* wr = W + (size_t)n*Dd + kc*32;
                int nv4 = (kc < 9) ? 8 : 3;        // kc=9: k 288..299 only
                #pragma unroll
                for (int i = 0; i < 8; ++i) {
                    if (i < nv4) {
                        float4 v = *(const float4*)(wr + i*4);
                        uu[2*i  ] = pk_rne(v.x, v.y);
                        uu[2*i+1] = pk_rne(v.z, v.w);
                    }
                }
            }
            unsigned fb = (unsigned)(sel*194560 + kc*19456 + n*16);
            #pragma unroll
            for (int g = 0; g < 4; ++g) {
                u4 q; q.x = uu[4*g+0]; q.y = uu[4*g+1]; q.z = uu[4*g+2]; q.w = uu[4*g+3];
                *(u4*)wadr(dout, fb + g*4864) = q;
            }
        }
        return;
    }
    // ---- row compaction for batch b: idx[b][0..cnt) = unmasked rows, asc --
    const int b = bx - 20;
    const int w = t >> 6, lane = t & 63;
    __shared__ int wtot[8], wbase[8];
    const int m = mask[b*Nn + t] != 0;
    unsigned long long bal = __ballot(m);
    if (lane == 0) wtot[w] = (int)__popcll(bal);
    __syncthreads();
    if (t == 0) {
        int s = 0;
        for (int i = 0; i < 8; ++i) { wbase[i] = s; s += wtot[i]; }
        *(int*)(ws + RCNT_OFF + b*4) = s;
    }
    __syncthreads();
    if (m) {
        int pos = wbase[w] + (int)__popcll(bal & ((1ull << lane) - 1ull));
        *(int*)(ws + RIDX_OFF + ((size_t)b*512 + pos)*4) = t;
    }
}

// ---------- Kernel B: fused projection GEMM (blocks 0..511) +  -------------
//            concepts->V-zone cast (blocks 512..1023, 2 tiles each)
__global__ __launch_bounds__(512)
void projcast(const float* __restrict__ concepts, const float* __restrict__ ocr,
              const float* __restrict__ bq, const float* __restrict__ bk,
              char* __restrict__ dout, char* __restrict__ tiles)
{
    __shared__ char Wl[2][19456];
    const int bx = blockIdx.x;
    const int t  = threadIdx.x;

    if (bx >= 512) {
        // ---- V-cast role: two (b,mt) tiles per block ----
        const int half = t >> 8, tt = t & 255;
        const int tileIdx = (bx - 512)*2 + half;
        const int mt = tileIdx & 15, b = tileIdx >> 4;
        char* vz = tiles + ((size_t)(b*16 + mt))*TSZ + VOFF;
        for (int task = tt; task < 300; task += 256) {
            int m8 = task / 75, d4 = task - m8*75;     // m8:0..3, d4:0..74
            const float* src = concepts + ((size_t)(b*Nn + mt*32 + m8*8))*Dd + d4*4;
            float4 r[8];
            #pragma unroll
            for (int i = 0; i < 8; ++i) r[i] = *(const float4*)(src + (size_t)i*Dd);
            #pragma unroll
            for (int dd = 0; dd < 4; ++dd) {
                int d = d4*4 + dd;
                float x[8];
                #pragma unroll
                for (int i = 0; i < 8; ++i)
                    x[i] = (dd==0) ? r[i].x : (dd==1) ? r[i].y : (dd==2) ? r[i].z : r[i].w;
                u4 q; q.x = pk_rne(x[0],x[1]); q.y = pk_rne(x[2],x[3]);
                      q.z = pk_rne(x[4],x[5]); q.w = pk_rne(x[6],x[7]);
                char* dst = (d < 288)
                    ? vz + (d>>4)*1024 + m8*256 + (d&15)*16
                    : vz + 18432 + m8*192 + (d-288)*16;
                *(u4*)dst = q;
            }
        }
        return;
    }

    // ---- projection role: 128 rows, 8 waves ----
    const int w = t >> 6, lane = t & 63, ln = lane & 15, quad = lane >> 4;
    const int sel = bx >> 8;
    const float* X    = sel ? ocr : concepts;
    const float* bias = sel ? bk  : bq;
    const int r0w = (bx & 255)*128 + w*16;
    const float* xr = X + (size_t)(r0w + ln)*Dd;

    const unsigned selbase = (unsigned)sel*194560u;
    #define STAGE_W8(buf, kc) \
        for (int c = w; c < 19; c += 8) \
            async16((const char*)wadr(dout, selbase + (unsigned)(kc)*19456u + c*1024u + lane*16u), \
                    &Wl[buf][c*1024 + lane*16]);

    f4 acc[19];
    #pragma unroll
    for (int i = 0; i < 19; ++i) acc[i] = (f4){0.f,0.f,0.f,0.f};

    STAGE_W8(0, 0);
    __syncthreads();

    for (int kc = 0; kc < 10; ++kc) {
        const int cur = kc & 1;
        if (kc < 9) { STAGE_W8(1 - cur, kc + 1); }
        BF a;
        if (kc < 9) {
            float4 v0 = *(const float4*)(xr + kc*32 + quad*8);
            float4 v1 = *(const float4*)(xr + kc*32 + quad*8 + 4);
            a.u[0]=pk_tr(v0.x,v0.y); a.u[1]=pk_tr(v0.z,v0.w);
            a.u[2]=pk_tr(v1.x,v1.y); a.u[3]=pk_tr(v1.z,v1.w);
        } else {
            a.u[0]=0; a.u[1]=0; a.u[2]=0; a.u[3]=0;
            if (quad == 0) {
                float4 v0 = *(const float4*)(xr + 288);
                float4 v1 = *(const float4*)(xr + 292);
                a.u[0]=pk_tr(v0.x,v0.y); a.u[1]=pk_tr(v0.z,v0.w);
                a.u[2]=pk_tr(v1.x,v1.y); a.u[3]=pk_tr(v1.z,v1.w);
            } else if (quad == 1) {
                float4 v0 = *(const float4*)(xr + 296);
                a.u[0]=pk_tr(v0.x,v0.y); a.u[1]=pk_tr(v0.z,v0.w);
            }
        }
        #pragma unroll
        for (int nt = 0; nt < 19; ++nt) {
            BF bfv; bfv.q = *(const u4*)&Wl[cur][quad*4864 + nt*256 + ln*16];
            acc[nt] = __builtin_amdgcn_mfma_f32_16x16x32_bf16(a.v, bfv.v, acc[nt], 0,0,0);
        }
        __syncthreads();
    }

    const float QSCALE = 0.057735026918962584f;   // 1/sqrt(300)
    #pragma unroll
    for (int nt = 0; nt < 19; ++nt) {
        int e = nt*16 + ln;
        if (sel == 0) {
            #pragma unroll
            for (int reg = 0; reg < 4; ++reg) {
                int r = r0w + quad*4 + reg;
                short val = (e < Dd) ? (short)bfr((acc[nt][reg] + bias[e])*QSCALE) : (short)0;
                *(short*)(dout + (size_t)r*1200 + e*2) = val;   // e 300..303 zeroed
            }
        } else if (e < Dd) {
            float bv = bias[e];
            #pragma unroll
            for (int reg = 0; reg < 4; ++reg) {
                int r = r0w + quad*4 + reg;
                int b = r >> 9, m = r & 511, mt = m >> 5, ml = m & 31;
                char* tile = tiles + ((size_t)(b*16 + mt))*TSZ;
                short val = (short)bfr(acc[nt][reg] + bv);
                if (e < 288)
                    *(short*)(tile + 768 + (e>>5)*2048 + ((e>>3)&3)*512 + ml*16 + (e&7)*2) = val;
                else
                    *(short*)(tile + ml*24 + (e-288)*2) = val;
            }
        }
    }
}

// stage one full 38400-B merged tile with 4 waves: 37 x 1KB + 512-B tail
#define STAGE_TILE4(SRC, DST) do { \
        const char* s_ = (SRC); char* d_ = (DST); \
        for (int c = w; c < 38; c += 4) \
            if (c < 37 || lane < 32) \
                async16(s_ + c*1024 + lane*16, d_ + c*1024 + lane*16); \
    } while (0)

// ---------- Kernel C: mask-compacted flash attention -----------------------
// Only unmasked rows (~50%) get attention: y in [0,5) covers up to 320
// compacted rows per batch in 4-wave/256-thread blocks of 64 rows (LDS-read
// demand per phase halves vs 8-wave: K/V frag reads are identical across
// waves). y == 5: masked-row fill (lnw+lnb) inside the same dispatch.
__global__ __launch_bounds__(256, 2)
void attnC(char* __restrict__ dout, char* __restrict__ ws,
           const float* __restrict__ ocr, const int* __restrict__ mask,
           const float* __restrict__ lnw, const float* __restrict__ lnb)
{
    const char* tiles = ws;
    const int t = threadIdx.x;
    const int w = t >> 6, lane = t & 63, ln = lane & 15, quad = lane >> 4;
    const int b = blockIdx.x;

    if (blockIdx.y == 5) {   // ---- masked-row fill role ----
        for (int i = w; i < Nn; i += 4) {
            int r = b*Nn + i;
            if (mask[r]) continue;
            for (int c = lane; c < Dd; c += 64)
                *(float*)(dout + (size_t)r*1200 + c*4) = lnw[c] + lnb[c];
        }
        return;
    }

    const int count = *(const int*)(ws + RCNT_OFF + b*4);
    const int n0c = blockIdx.y*64;
    if (n0c >= count) return;
    const int* idxb = (const int*)(ws + RIDX_OFF + (size_t)b*512*4);

    __shared__ __align__(16) char Tb[2][TSZ];

    // Q B-frags via compacted row index (per-lane gather; clamped padding)
    int jq = n0c + w*16 + ln;
    if (jq >= count) jq = count - 1;
    const int rq = idxb[jq];                       // local row 0..511
    const char* qb = dout + ((size_t)b*Nn + rq)*1200;
    bfrag qf[10];
    #pragma unroll
    for (int kc = 0; kc < 9; ++kc)
        qf[kc] = *(const bfrag*)(qb + kc*64 + quad*16);
    {
        BF z; z.u[0]=z.u[1]=z.u[2]=z.u[3]=0;
        if (quad < 2) z.q = *(const u4*)(qb + 576 + quad*16);
        qf[9] = z.v;
    }

    f4 oacc[19];
    #pragma unroll
    for (int i = 0; i < 19; ++i) oacc[i] = (f4){0.f,0.f,0.f,0.f};
    float lrun = 0.f;
    const char* tb = tiles + (size_t)b*16*TSZ;

    STAGE_TILE4(tb, Tb[0]);
    __syncthreads();

    for (int mt = 0; mt < 16; ++mt) {
        const char* Kz = Tb[mt & 1];
        const char* Vz = Kz + VOFF;
        if (mt < 15) STAGE_TILE4(tb + (size_t)(mt+1)*TSZ, Tb[1 - (mt & 1)]);

        // S^T: A = K rows (m), B = Q  ->  C: row=m=quad*4+reg, col=n=ln
        f4 slo = (f4){0.f,0.f,0.f,0.f}, shi = (f4){0.f,0.f,0.f,0.f};
        __builtin_amdgcn_s_setprio(1);
        #pragma unroll
        for (int kc = 0; kc < 9; ++kc) {
            bfrag alo = *(const bfrag*)(Kz + 768 + kc*2048 + quad*512 + ln*16);
            bfrag ahi = *(const bfrag*)(Kz + 768 + kc*2048 + quad*512 + 256 + ln*16);
            slo = __builtin_amdgcn_mfma_f32_16x16x32_bf16(alo, qf[kc], slo, 0,0,0);
            shi = __builtin_amdgcn_mfma_f32_16x16x32_bf16(ahi, qf[kc], shi, 0,0,0);
        }
        {   // kc = 9 from 24B-row sub-tile (k>=300 garbage killed by Q zeros)
            BF alo, ahi;
            alo.u[0]=alo.u[1]=alo.u[2]=alo.u[3]=0;
            ahi.u[0]=ahi.u[1]=ahi.u[2]=ahi.u[3]=0;
            if (quad < 2) {
                u2 x0 = *(const u2*)(Kz + ln*24 + quad*16);
                u2 x1 = *(const u2*)(Kz + ln*24 + quad*16 + 8);
                alo.u[0]=x0.x; alo.u[1]=x0.y; alo.u[2]=x1.x; alo.u[3]=x1.y;
                u2 y0 = *(const u2*)(Kz + (16+ln)*24 + quad*16);
                u2 y1 = *(const u2*)(Kz + (16+ln)*24 + quad*16 + 8);
                ahi.u[0]=y0.x; ahi.u[1]=y0.y; ahi.u[2]=y1.x; ahi.u[3]=y1.y;
            }
            slo = __builtin_amdgcn_mfma_f32_16x16x32_bf16(alo.v, qf[9], slo, 0,0,0);
            shi = __builtin_amdgcn_mfma_f32_16x16x32_bf16(ahi.v, qf[9], shi, 0,0,0);
        }
        __builtin_amdgcn_s_setprio(0);

        // unnormalized softmax: p = exp(s), l += sum(p)  (register-only)
        float elo[4], ehi[4], ls = 0.f;
        #pragma unroll
        for (int reg = 0; reg < 4; ++reg) {
            elo[reg] = __expf(slo[reg]);
            ehi[reg] = __expf(shi[reg]);
            ls += elo[reg] + ehi[reg];
        }
        ls += __shfl_xor(ls, 16);
        ls += __shfl_xor(ls, 32);
        lrun += ls;

        // P: C-layout -> A-layout in-register (8 shfl + select)
        unsigned lo01 = pk_rne(elo[0], elo[1]), lo23 = pk_rne(elo[2], elo[3]);
        unsigned hi01 = pk_rne(ehi[0], ehi[1]), hi23 = pk_rne(ehi[2], ehi[3]);
        int sA = 2*(quad & 1)*16 + ln, sB = sA + 16;
        unsigned l0 = (unsigned)__shfl((int)lo01, sA);
        unsigned l1 = (unsigned)__shfl((int)lo23, sA);
        unsigned l2 = (unsigned)__shfl((int)lo01, sB);
        unsigned l3 = (unsigned)__shfl((int)lo23, sB);
        unsigned h0 = (unsigned)__shfl((int)hi01, sA);
        unsigned h1 = (unsigned)__shfl((int)hi23, sA);
        unsigned h2 = (unsigned)__shfl((int)hi01, sB);
        unsigned h3 = (unsigned)__shfl((int)hi23, sB);
        BF p;
        bool useHi = quad >= 2;
        p.u[0] = useHi ? h0 : l0; p.u[1] = useHi ? h1 : l1;
        p.u[2] = useHi ? h2 : l2; p.u[3] = useHi ? h3 : l3;

        // O += P V : B-frags from V zone of the LDS tile
        __builtin_amdgcn_s_setprio(1);
        #pragma unroll
        for (int nt = 0; nt < 18; ++nt) {
            bfrag vf = *(const bfrag*)(Vz + nt*1024 + lane*16);
            oacc[nt] = __builtin_amdgcn_mfma_f32_16x16x32_bf16(p.v, vf, oacc[nt], 0,0,0);
        }
        {   // nt = 18: d 288..303, ln >= 12 has no storage -> zero frag
            BF vf; vf.u[0]=vf.u[1]=vf.u[2]=vf.u[3]=0;
            if (ln < 12) vf.q = *(const u4*)(Vz + 18432 + quad*192 + ln*16);
            oacc[18] = __builtin_amdgcn_mfma_f32_16x16x32_bf16(p.v, vf.v, oacc[18], 0,0,0);
        }
        __builtin_amdgcn_s_setprio(0);

        __syncthreads();   // drains stage(mt+1); marks current buffer free
    }

    // epilogue: compacted rows j = n0c + w*16 + quad*4 + reg (all unmasked)
    float invl[4];
    #pragma unroll
    for (int reg = 0; reg < 4; ++reg) invl[reg] = 1.0f / __shfl(lrun, quad*4 + reg);
    #pragma unroll
    for (int reg = 0; reg < 4; ++reg) {
        int jr = n0c + w*16 + quad*4 + reg;
        if (jr >= count) continue;                 // uniform within a quad
        int r = b*Nn + idxb[jr];
        float xs[19], s = 0.f, ss = 0.f;
        #pragma unroll
        for (int nt = 0; nt < 19; ++nt) {
            int d = nt*16 + ln;
            float x = 0.f;
            if (d < Dd) x = oacc[nt][reg]*invl[reg] + ocr[(size_t)r*Dd + d];
            xs[nt] = x; s += x; ss += x*x;
        }
        #pragma unroll
        for (int off = 1; off < 16; off <<= 1) {
            s += __shfl_xor(s, off); ss += __shfl_xor(ss, off);
        }
        float mu   = s * (1.0f/Dd);
        float var  = ss * (1.0f/Dd) - mu*mu;
        float rstd = rsqrtf(var + 1e-5f);
        #pragma unroll
        for (int nt = 0; nt < 19; ++nt) {
            int d = nt*16 + ln;
            if (d < Dd)
                *(float*)(dout + (size_t)r*1200 + d*4) = (xs[nt]-mu)*rstd*lnw[d] + lnb[d];
        }
    }
}

extern "C" void kernel_launch(void* const* d_in, const int* in_sizes, int n_in,
                              void* d_out, int out_size, void* d_ws, size_t ws_size,
                              hipStream_t stream)
{
    const float* concepts = (const float*)d_in[0];
    const float* ocr      = (const float*)d_in[1];
    const int*   mask     = (const int*)d_in[2];
    const float* wq  = (const float*)d_in[3];
    const float* bq  = (const float*)d_in[4];
    const float* wk  = (const float*)d_in[5];
    const float* bk  = (const float*)d_in[6];
    const float* lnw = (const float*)d_in[7];
    const float* lnb = (const float*)d_in[8];

    char* dout  = (char*)d_out;
    char* tiles = (char*)d_ws;   // merged tiles at offset 0; idx/cnt after

    wridx   <<<dim3(84),    512, 0, stream>>>(wq, wk, mask, dout, (char*)d_ws);
    projcast<<<dim3(1024),  512, 0, stream>>>(concepts, ocr, bq, bk, dout, tiles);
    attnC   <<<dim3(64, 6), 256, 0, stream>>>(dout, (char*)d_ws, ocr, mask, lnw, lnb);
}

// Round 10
// 215.238 us; speedup vs baseline: 1.2236x; 1.0724x over previous
//
#include <hip/hip_runtime.h>
#include <math.h>

#define Bb 64
#define Nn 512
#define Dd 300

typedef __attribute__((ext_vector_type(8))) short bfrag;   // 8 bf16 = 4 VGPRs
typedef __attribute__((ext_vector_type(4))) float f4;      // MFMA accumulator
typedef __attribute__((ext_vector_type(4))) unsigned u4;
typedef __attribute__((ext_vector_type(2))) unsigned u2;

union BF { unsigned u[4]; bfrag v; u4 q; };

__device__ inline unsigned bfr(float x){            // f32 -> bf16 bits, RNE
    union{float f;unsigned u;}v; v.f=x;
    return (v.u + 0x7FFFu + ((v.u>>16)&1u))>>16;
}
__device__ inline unsigned pk_rne(float a, float b){ return bfr(a) | (bfr(b)<<16); }
__device__ inline unsigned pk_tr(float a, float b){  // truncation pack (cheap)
    union{float f;unsigned u;} ua, ub; ua.f=a; ub.f=b;
    return (ua.u>>16) | (ub.u & 0xFFFF0000u);
}
// W-frag bytes live in d_out slot bytes [608, 608+512) of slots f>>9
__device__ inline char* wadr(char* dout, unsigned f){
    return dout + (size_t)(f>>9)*1200u + 608u + (f&511u);
}
__device__ inline void async16(const char* g, char* l){
    __builtin_amdgcn_global_load_lds(
        (const __attribute__((address_space(1))) void*)g,
        (__attribute__((address_space(3))) void*)l, 16, 0, 0);
}

// Merged (b,mt) tile: 38400 B = [K zone 19200 | V zone 19200]
//  K: kc9 sub-tile [0,768): m*24 + (e-288)*2
//     kc<9:  768 + kc*2048 + ((e>>3)&3)*512 + m*16 + (e&7)*2
//  V: d<288:  19200 + (d>>4)*1024 + (m>>3)*256 + (d&15)*16 + (m&7)*2
//     d>=288: 19200 + 18432 + (m>>3)*192 + (d-288)*16 + (m&7)*2
#define TSZ 38400
#define VOFF 19200

// ---------- Kernel A: W -> bf16 frag-tiles in d_out high bytes -------------
// f = sel*194560 + kc*19456 + g*4864 + n*16  (+ (k&7)*2 inside)
__global__ __launch_bounds__(256)
void wprep(const float* __restrict__ wq, const float* __restrict__ wk,
           char* __restrict__ dout)
{
    const int sel = blockIdx.x / 10, kc = blockIdx.x % 10;
    const float* W = sel ? wk : wq;
    const int n = blockIdx.y*152 + threadIdx.x;
    if (threadIdx.x < 152 && n < 304) {
        unsigned uu[16];
        #pragma unroll
        for (int j = 0; j < 16; ++j) uu[j] = 0;
        if (n < Dd) {
            const float* wr = W + (size_t)n*Dd + kc*32;
            int nv4 = (kc < 9) ? 8 : 3;        // kc=9: k 288..299 only
            #pragma unroll
            for (int i = 0; i < 8; ++i) {
                if (i < nv4) {
                    float4 v = *(const float4*)(wr + i*4);
                    uu[2*i  ] = pk_rne(v.x, v.y);
                    uu[2*i+1] = pk_rne(v.z, v.w);
                }
            }
        }
        unsigned fb = (unsigned)(sel*194560 + kc*19456 + n*16);
        #pragma unroll
        for (int g = 0; g < 4; ++g) {
            u4 q; q.x = uu[4*g+0]; q.y = uu[4*g+1]; q.z = uu[4*g+2]; q.w = uu[4*g+3];
            *(u4*)wadr(dout, fb + g*4864) = q;
        }
    }
}

// ---------- Kernel B: fused projection GEMM (blocks 0..511) +  -------------
//            concepts->V-zone cast (blocks 512..1023, 2 tiles each)
__global__ __launch_bounds__(512)
void projcast(const float* __restrict__ concepts, const float* __restrict__ ocr,
              const float* __restrict__ bq, const float* __restrict__ bk,
              char* __restrict__ dout, char* __restrict__ tiles)
{
    __shared__ char Wl[2][19456];
    const int bx = blockIdx.x;
    const int t  = threadIdx.x;

    if (bx >= 512) {
        // ---- V-cast role: two (b,mt) tiles per block ----
        const int half = t >> 8, tt = t & 255;
        const int tileIdx = (bx - 512)*2 + half;
        const int mt = tileIdx & 15, b = tileIdx >> 4;
        char* vz = tiles + ((size_t)(b*16 + mt))*TSZ + VOFF;
        for (int task = tt; task < 300; task += 256) {
            int m8 = task / 75, d4 = task - m8*75;     // m8:0..3, d4:0..74
            const float* src = concepts + ((size_t)(b*Nn + mt*32 + m8*8))*Dd + d4*4;
            float4 r[8];
            #pragma unroll
            for (int i = 0; i < 8; ++i) r[i] = *(const float4*)(src + (size_t)i*Dd);
            #pragma unroll
            for (int dd = 0; dd < 4; ++dd) {
                int d = d4*4 + dd;
                float x[8];
                #pragma unroll
                for (int i = 0; i < 8; ++i)
                    x[i] = (dd==0) ? r[i].x : (dd==1) ? r[i].y : (dd==2) ? r[i].z : r[i].w;
                u4 q; q.x = pk_rne(x[0],x[1]); q.y = pk_rne(x[2],x[3]);
                      q.z = pk_rne(x[4],x[5]); q.w = pk_rne(x[6],x[7]);
                char* dst = (d < 288)
                    ? vz + (d>>4)*1024 + m8*256 + (d&15)*16
                    : vz + 18432 + m8*192 + (d-288)*16;
                *(u4*)dst = q;
            }
        }
        return;
    }

    // ---- projection role: 128 rows, 8 waves ----
    const int w = t >> 6, lane = t & 63, ln = lane & 15, quad = lane >> 4;
    const int sel = bx >> 8;
    const float* X    = sel ? ocr : concepts;
    const float* bias = sel ? bk  : bq;
    const int r0w = (bx & 255)*128 + w*16;
    const float* xr = X + (size_t)(r0w + ln)*Dd;

    const unsigned selbase = (unsigned)sel*194560u;
    #define STAGE_W8(buf, kc) \
        for (int c = w; c < 19; c += 8) \
            async16((const char*)wadr(dout, selbase + (unsigned)(kc)*19456u + c*1024u + lane*16u), \
                    &Wl[buf][c*1024 + lane*16]);

    f4 acc[19];
    #pragma unroll
    for (int i = 0; i < 19; ++i) acc[i] = (f4){0.f,0.f,0.f,0.f};

    STAGE_W8(0, 0);
    __syncthreads();

    for (int kc = 0; kc < 10; ++kc) {
        const int cur = kc & 1;
        if (kc < 9) { STAGE_W8(1 - cur, kc + 1); }
        BF a;
        if (kc < 9) {
            float4 v0 = *(const float4*)(xr + kc*32 + quad*8);
            float4 v1 = *(const float4*)(xr + kc*32 + quad*8 + 4);
            a.u[0]=pk_tr(v0.x,v0.y); a.u[1]=pk_tr(v0.z,v0.w);
            a.u[2]=pk_tr(v1.x,v1.y); a.u[3]=pk_tr(v1.z,v1.w);
        } else {
            a.u[0]=0; a.u[1]=0; a.u[2]=0; a.u[3]=0;
            if (quad == 0) {
                float4 v0 = *(const float4*)(xr + 288);
                float4 v1 = *(const float4*)(xr + 292);
                a.u[0]=pk_tr(v0.x,v0.y); a.u[1]=pk_tr(v0.z,v0.w);
                a.u[2]=pk_tr(v1.x,v1.y); a.u[3]=pk_tr(v1.z,v1.w);
            } else if (quad == 1) {
                float4 v0 = *(const float4*)(xr + 296);
                a.u[0]=pk_tr(v0.x,v0.y); a.u[1]=pk_tr(v0.z,v0.w);
            }
        }
        #pragma unroll
        for (int nt = 0; nt < 19; ++nt) {
            BF bfv; bfv.q = *(const u4*)&Wl[cur][quad*4864 + nt*256 + ln*16];
            acc[nt] = __builtin_amdgcn_mfma_f32_16x16x32_bf16(a.v, bfv.v, acc[nt], 0,0,0);
        }
        __syncthreads();
    }

    const float QSCALE = 0.057735026918962584f;   // 1/sqrt(300)
    #pragma unroll
    for (int nt = 0; nt < 19; ++nt) {
        int e = nt*16 + ln;
        if (sel == 0) {
            #pragma unroll
            for (int reg = 0; reg < 4; ++reg) {
                int r = r0w + quad*4 + reg;
                short val = (e < Dd) ? (short)bfr((acc[nt][reg] + bias[e])*QSCALE) : (short)0;
                *(short*)(dout + (size_t)r*1200 + e*2) = val;   // e 300..303 zeroed
            }
        } else if (e < Dd) {
            float bv = bias[e];
            #pragma unroll
            for (int reg = 0; reg < 4; ++reg) {
                int r = r0w + quad*4 + reg;
                int b = r >> 9, m = r & 511, mt = m >> 5, ml = m & 31;
                char* tile = tiles + ((size_t)(b*16 + mt))*TSZ;
                short val = (short)bfr(acc[nt][reg] + bv);
                if (e < 288)
                    *(short*)(tile + 768 + (e>>5)*2048 + ((e>>3)&3)*512 + ml*16 + (e&7)*2) = val;
                else
                    *(short*)(tile + ml*24 + (e-288)*2) = val;
            }
        }
    }
}

// ---------- Kernel D: attn with counted-vmcnt 2-deep staging pipeline ------
// All 7 prior variants obeyed: per-CU time = tile-stages x ~4us, because
// __syncthreads drains vmcnt(0) -- the just-issued prefetch -- every phase
// (the m97 barrier-drain mechanism). This version: 3-buffer LDS, stage(p+2)
// issued at phase-p top, end-of-phase wait = inline-asm s_waitcnt vmcnt(5)
// + raw s_barrier: only stage(p+1) must have landed; stage(p+2)'s 5 loads
// per wave stay in flight across the barrier. Uniform 5 global_load_lds per
// wave per stage (waves 6,7 issue a dummy 5th into Pad) so the compile-time
// count is exact for every wave. Q-loads drained once in the prologue.
__global__ __launch_bounds__(512, 2)
void attnD(char* __restrict__ dout, const char* __restrict__ tiles,
           const float* __restrict__ ocr, const int* __restrict__ mask,
           const float* __restrict__ lnw, const float* __restrict__ lnb)
{
    __shared__ __align__(16) char Tb[3][TSZ];
    __shared__ __align__(16) char Pad[2048];       // dummy-load sink (w=6,7)
    const int t = threadIdx.x;
    const int w = t >> 6, lane = t & 63, ln = lane & 15, quad = lane >> 4;
    const int b = blockIdx.x, n0 = blockIdx.y*128;  // same-b blocks share an XCD
    const int nlane = n0 + w*16 + ln;

    // exactly 5 async16 per wave per stage: c = w + 8i; c==37 is the 512-B
    // tail (lane<32, still 1 wave-instruction); c>=38 -> dummy into Pad
#define STAGE3(SRC, DST) do { \
        const char* s_ = (SRC); char* d_ = (DST); \
        _Pragma("unroll") \
        for (int i = 0; i < 5; ++i) { \
            int c = w + i*8; \
            if (c < 37) async16(s_ + c*1024 + lane*16, d_ + c*1024 + lane*16); \
            else if (c == 37) { if (lane < 32) async16(s_ + 37*1024 + lane*16, d_ + 37*1024 + lane*16); } \
            else async16(s_ + lane*16, Pad + (c - 38)*1024 + lane*16); \
        } \
    } while (0)

    // Q B-frags from d_out low bytes (prescaled by 1/sqrt(300))
    const char* qb = dout + (size_t)(b*Nn + nlane)*1200;
    bfrag qf[10];
    #pragma unroll
    for (int kc = 0; kc < 9; ++kc)
        qf[kc] = *(const bfrag*)(qb + kc*64 + quad*16);
    {
        BF z; z.u[0]=z.u[1]=z.u[2]=z.u[3]=0;
        if (quad < 2) z.q = *(const u4*)(qb + 576 + quad*16);
        qf[9] = z.v;
    }
    // drain Q loads so vmem counts below track staging only
    asm volatile("s_waitcnt vmcnt(0)" ::: "memory");

    f4 oacc[19];
    #pragma unroll
    for (int i = 0; i < 19; ++i) oacc[i] = (f4){0.f,0.f,0.f,0.f};
    float lrun = 0.f;
    const char* tb = tiles + (size_t)b*16*TSZ;

    STAGE3(tb,            Tb[0]);                  // stage(0): 5/wave
    STAGE3(tb + TSZ,      Tb[1]);                  // stage(1): 5/wave
    asm volatile("s_waitcnt vmcnt(5)" ::: "memory");   // stage(0) landed
    __builtin_amdgcn_s_barrier();
    __builtin_amdgcn_sched_barrier(0);

    for (int mt = 0; mt < 16; ++mt) {
        const char* Kz = Tb[mt % 3];
        const char* Vz = Kz + VOFF;

        // issue stage(mt+2); it has TWO compute phases before its drain
        if (mt < 14) STAGE3(tb + (size_t)(mt+2)*TSZ, Tb[(mt+2) % 3]);

        // S^T: A = K rows (m), B = Q  ->  C: row=m=quad*4+reg, col=n=ln
        f4 slo = (f4){0.f,0.f,0.f,0.f}, shi = (f4){0.f,0.f,0.f,0.f};
        __builtin_amdgcn_s_setprio(1);
        #pragma unroll
        for (int kc = 0; kc < 9; ++kc) {
            bfrag alo = *(const bfrag*)(Kz + 768 + kc*2048 + quad*512 + ln*16);
            bfrag ahi = *(const bfrag*)(Kz + 768 + kc*2048 + quad*512 + 256 + ln*16);
            slo = __builtin_amdgcn_mfma_f32_16x16x32_bf16(alo, qf[kc], slo, 0,0,0);
            shi = __builtin_amdgcn_mfma_f32_16x16x32_bf16(ahi, qf[kc], shi, 0,0,0);
        }
        {   // kc = 9 from 24B-row sub-tile (k>=300 garbage killed by Q zeros)
            BF alo, ahi;
            alo.u[0]=alo.u[1]=alo.u[2]=alo.u[3]=0;
            ahi.u[0]=ahi.u[1]=ahi.u[2]=ahi.u[3]=0;
            if (quad < 2) {
                u2 x0 = *(const u2*)(Kz + ln*24 + quad*16);
                u2 x1 = *(const u2*)(Kz + ln*24 + quad*16 + 8);
                alo.u[0]=x0.x; alo.u[1]=x0.y; alo.u[2]=x1.x; alo.u[3]=x1.y;
                u2 y0 = *(const u2*)(Kz + (16+ln)*24 + quad*16);
                u2 y1 = *(const u2*)(Kz + (16+ln)*24 + quad*16 + 8);
                ahi.u[0]=y0.x; ahi.u[1]=y0.y; ahi.u[2]=y1.x; ahi.u[3]=y1.y;
            }
            slo = __builtin_amdgcn_mfma_f32_16x16x32_bf16(alo.v, qf[9], slo, 0,0,0);
            shi = __builtin_amdgcn_mfma_f32_16x16x32_bf16(ahi.v, qf[9], shi, 0,0,0);
        }
        __builtin_amdgcn_s_setprio(0);

        // unnormalized softmax: p = exp(s), l += sum(p)  (register-only)
        float elo[4], ehi[4], ls = 0.f;
        #pragma unroll
        for (int reg = 0; reg < 4; ++reg) {
            elo[reg] = __expf(slo[reg]);
            ehi[reg] = __expf(shi[reg]);
            ls += elo[reg] + ehi[reg];
        }
        ls += __shfl_xor(ls, 16);
        ls += __shfl_xor(ls, 32);
        lrun += ls;

        // P: C-layout -> A-layout in-register (8 shfl + select)
        unsigned lo01 = pk_rne(elo[0], elo[1]), lo23 = pk_rne(elo[2], elo[3]);
        unsigned hi01 = pk_rne(ehi[0], ehi[1]), hi23 = pk_rne(ehi[2], ehi[3]);
        int sA = 2*(quad & 1)*16 + ln, sB = sA + 16;
        unsigned l0 = (unsigned)__shfl((int)lo01, sA);
        unsigned l1 = (unsigned)__shfl((int)lo23, sA);
        unsigned l2 = (unsigned)__shfl((int)lo01, sB);
        unsigned l3 = (unsigned)__shfl((int)lo23, sB);
        unsigned h0 = (unsigned)__shfl((int)hi01, sA);
        unsigned h1 = (unsigned)__shfl((int)hi23, sA);
        unsigned h2 = (unsigned)__shfl((int)hi01, sB);
        unsigned h3 = (unsigned)__shfl((int)hi23, sB);
        BF p;
        bool useHi = quad >= 2;
        p.u[0] = useHi ? h0 : l0; p.u[1] = useHi ? h1 : l1;
        p.u[2] = useHi ? h2 : l2; p.u[3] = useHi ? h3 : l3;

        // O += P V : B-frags from V zone of the LDS tile
        __builtin_amdgcn_s_setprio(1);
        #pragma unroll
        for (int nt = 0; nt < 18; ++nt) {
            bfrag vf = *(const bfrag*)(Vz + nt*1024 + lane*16);
            oacc[nt] = __builtin_amdgcn_mfma_f32_16x16x32_bf16(p.v, vf, oacc[nt], 0,0,0);
        }
        {   // nt = 18: d 288..303, ln >= 12 has no storage -> zero frag
            BF vf; vf.u[0]=vf.u[1]=vf.u[2]=vf.u[3]=0;
            if (ln < 12) vf.q = *(const u4*)(Vz + 18432 + quad*192 + ln*16);
            oacc[18] = __builtin_amdgcn_mfma_f32_16x16x32_bf16(p.v, vf.v, oacc[18], 0,0,0);
        }
        __builtin_amdgcn_s_setprio(0);

        // end-of-phase: stage(mt+1) must be landed; stage(mt+2) stays in
        // flight (5 loads/wave). All LDS reads of this phase were consumed
        // by MFMAs above (compiler lgkmcnt) -> safe to re-stage next phase.
        if (mt < 14) { asm volatile("s_waitcnt vmcnt(5)" ::: "memory"); }
        else         { asm volatile("s_waitcnt vmcnt(0)" ::: "memory"); }
        __builtin_amdgcn_s_barrier();
        __builtin_amdgcn_sched_barrier(0);
    }

    // epilogue: rows n = quad*4+reg; cols d = nt*16+ln
    float invl[4];
    #pragma unroll
    for (int reg = 0; reg < 4; ++reg) invl[reg] = 1.0f / __shfl(lrun, quad*4 + reg);
    #pragma unroll
    for (int reg = 0; reg < 4; ++reg) {
        int r = b*Nn + n0 + w*16 + quad*4 + reg;
        int mr = mask[r];
        float xs[19], s = 0.f, ss = 0.f;
        #pragma unroll
        for (int nt = 0; nt < 19; ++nt) {
            int d = nt*16 + ln;
            float x = 0.f;
            if (d < Dd) x = oacc[nt][reg]*invl[reg] + ocr[(size_t)r*Dd + d];
            xs[nt] = x; s += x; ss += x*x;
        }
        #pragma unroll
        for (int off = 1; off < 16; off <<= 1) {
            s += __shfl_xor(s, off); ss += __shfl_xor(ss, off);
        }
        float mu   = s * (1.0f/Dd);
        float var  = ss * (1.0f/Dd) - mu*mu;
        float rstd = rsqrtf(var + 1e-5f);
        #pragma unroll
        for (int nt = 0; nt < 19; ++nt) {
            int d = nt*16 + ln;
            if (d < Dd) {
                // masked rows: +lnw+lnb (verified rounds 1-5)
                float y = mr ? (xs[nt]-mu)*rstd*lnw[d] + lnb[d] : lnw[d] + lnb[d];
                *(float*)(dout + (size_t)r*1200 + d*4) = y;
            }
        }
    }
}

extern "C" void kernel_launch(void* const* d_in, const int* in_sizes, int n_in,
                              void* d_out, int out_size, void* d_ws, size_t ws_size,
                              hipStream_t stream)
{
    const float* concepts = (const float*)d_in[0];
    const float* ocr      = (const float*)d_in[1];
    const int*   mask     = (const int*)d_in[2];
    const float* wq  = (const float*)d_in[3];
    const float* bq  = (const float*)d_in[4];
    const float* wk  = (const float*)d_in[5];
    const float* bk  = (const float*)d_in[6];
    const float* lnw = (const float*)d_in[7];
    const float* lnb = (const float*)d_in[8];

    char* dout  = (char*)d_out;
    char* tiles = (char*)d_ws;   // 1024 merged tiles x 38400 B = 39,321,600 B

    wprep   <<<dim3(20, 2), 256, 0, stream>>>(wq, wk, dout);
    projcast<<<dim3(1024),  512, 0, stream>>>(concepts, ocr, bq, bk, dout, tiles);
    attnD   <<<dim3(64, 4), 512, 0, stream>>>(dout, tiles, ocr, mask, lnw, lnb);
}